// Round 4
// baseline (98.067 us; speedup 1.0000x reference)
//
#include <hip/hip_runtime.h>

// color_entropy_loss: x [32,3,512,512] f32 -> scalar f32
//   temp = (x*255).mean(axis=1); idx = clip(int(temp),0,255)
//   per-batch 256-bin histogram; hist[0] forced to H*W; hist += 1
//   prob = hist/(H*W+256); loss = mean_b( sum(prob*log(prob)) )
//
// R4: fully fused single kernel. Per-wave LDS histograms -> global atomic
// merge into 32x256 hist -> last-block-done (threadfence + counter) computes
// entropy and writes the scalar. One memset node + one kernel dispatch.

constexpr int BATCH = 32;
constexpr int HW_ = 512 * 512;      // 262144
constexpr int BINS = 256;
constexpr int THREADS = 256;
constexpr int BPB = 32;                                   // blocks per batch -> 1024 blocks
constexpr int GROUPS_PER_BLOCK = (HW_ / 4) / BPB;         // 2048 float4 groups
constexpr int GPT = GROUPS_PER_BLOCK / THREADS;           // 8 groups per thread
constexpr int UNROLL = 4;
constexpr int PASSES = GPT / UNROLL;                      // 2
constexpr unsigned TOTAL_BLOCKS = BPB * BATCH;            // 1024

__global__ __launch_bounds__(THREADS) void hist_fused(const float* __restrict__ x,
                                                      unsigned* __restrict__ hist,
                                                      unsigned* __restrict__ counter,
                                                      float* __restrict__ out) {
    // Per-wave privatized histograms: 4 waves * 256 bins * 4B = 4 KiB LDS
    __shared__ unsigned lh[4][BINS];
    __shared__ unsigned islast;
    __shared__ float red[256];
    const int t = threadIdx.x;
    const int wave = t >> 6;
#pragma unroll
    for (int w = 0; w < 4; ++w) lh[w][t] = 0u;
    __syncthreads();

    const int b = blockIdx.y;
    const float* base = x + (size_t)b * 3 * HW_;
    const float4* __restrict__ p0 = (const float4*)(base);
    const float4* __restrict__ p1 = (const float4*)(base + HW_);
    const float4* __restrict__ p2 = (const float4*)(base + 2 * HW_);
    const int g0 = blockIdx.x * GROUPS_PER_BLOCK + t;

#pragma unroll
    for (int pass = 0; pass < PASSES; ++pass) {
        float4 A[UNROLL], Bc[UNROLL], Cc[UNROLL];
#pragma unroll
        for (int u = 0; u < UNROLL; ++u) {
            int g = g0 + (pass * UNROLL + u) * THREADS;
            A[u]  = p0[g];
            Bc[u] = p1[g];
            Cc[u] = p2[g];
        }
#pragma unroll
        for (int u = 0; u < UNROLL; ++u) {
            // mean(x*255) = (a+b+c)*85 up to rounding; bin flips only at
            // integer boundaries (~1e-5 loss effect per flip, thr=0.103)
            float t0 = ((A[u].x + Bc[u].x) + Cc[u].x) * 85.0f;
            float t1 = ((A[u].y + Bc[u].y) + Cc[u].y) * 85.0f;
            float t2 = ((A[u].z + Bc[u].z) + Cc[u].z) * 85.0f;
            float t3 = ((A[u].w + Bc[u].w) + Cc[u].w) * 85.0f;
            int i0 = min(max((int)t0, 0), 255);   // trunc == astype(int32)
            int i1 = min(max((int)t1, 0), 255);
            int i2 = min(max((int)t2, 0), 255);
            int i3 = min(max((int)t3, 0), 255);
            atomicAdd(&lh[wave][i0], 1u);
            atomicAdd(&lh[wave][i1], 1u);
            atomicAdd(&lh[wave][i2], 1u);
            atomicAdd(&lh[wave][i3], 1u);
        }
    }
    __syncthreads();

    // Merge into per-batch global histogram (device-scope atomics)
    unsigned total = lh[0][t] + lh[1][t] + lh[2][t] + lh[3][t];
    if (total) atomicAdd(&hist[b * BINS + t], total);

    // Last-block-done: device fence, then count arrivals
    __threadfence();
    if (t == 0) {
        unsigned old = atomicAdd(counter, 1u);
        islast = (old == TOTAL_BLOCKS - 1) ? 1u : 0u;
    }
    __syncthreads();
    if (!islast) return;

    // Entropy: thread t owns bin t across all batches; coherent atomic reads
    const float inv_np = 1.0f / (float)(HW_ + BINS);       // 1/262400
    float s = 0.0f;
#pragma unroll 4
    for (int bb = 0; bb < BATCH; ++bb) {
        unsigned cnt = atomicAdd(&hist[bb * BINS + t], 0u);   // L2-coherent read
        // bin-0 quirk: counts[:,0] = H*W, then +1 smoothing on every bin
        float h = (t == 0) ? ((float)HW_ + 1.0f) : ((float)cnt + 1.0f);
        float p = h * inv_np;
        s += p * logf(p);
    }
    red[t] = s;
    __syncthreads();
    for (int off = 128; off > 0; off >>= 1) {
        if (t < off) red[t] += red[t + off];
        __syncthreads();
    }
    if (t == 0) out[0] = red[0] * (1.0f / (float)BATCH);
}

extern "C" void kernel_launch(void* const* d_in, const int* in_sizes, int n_in,
                              void* d_out, int out_size, void* d_ws, size_t ws_size,
                              hipStream_t stream) {
    const float* x = (const float*)d_in[0];
    float* out = (float*)d_out;
    unsigned* hist = (unsigned*)d_ws;                  // 32*256 u32 = 32 KiB
    unsigned* counter = hist + BATCH * BINS;           // 1 u32

    // Zero hist + counter (ws is poisoned, and determinism requires reset)
    hipMemsetAsync(d_ws, 0, (BATCH * BINS + 1) * sizeof(unsigned), stream);
    hist_fused<<<dim3(BPB, BATCH), dim3(THREADS), 0, stream>>>(x, hist, counter, out);
}

// Round 5
// 40.724 us; speedup vs baseline: 2.4081x; 2.4081x over previous
//
#include <hip/hip_runtime.h>

// color_entropy_loss: x [32,3,512,512] f32 -> scalar f32
//   temp = (x*255).mean(axis=1); idx = clip(int(temp),0,255)
//   per-batch 256-bin histogram; hist[0] forced to H*W; hist += 1
//   prob = hist/(H*W+256); loss = mean_b( sum(prob*log(prob)) )
//
// R5: fused single kernel, NO __threadfence (R4's 1024 per-block device
// fences each forced an L2 writeback/invalidate -> 5x regression). All
// cross-block communication is via device-coherent-point atomics:
//   - hist merge: atomicAdd (coherent point, no fence needed)
//   - ordering:  __syncthreads() drains vmcnt(0) per wave before counter bump
//   - tail reads: agent-scope relaxed atomic loads (bypass stale L1/L2)

constexpr int BATCH = 32;
constexpr int HW_ = 512 * 512;      // 262144
constexpr int BINS = 256;
constexpr int THREADS = 256;
constexpr int BPB = 32;                                   // blocks per batch -> 1024 blocks
constexpr int GROUPS_PER_BLOCK = (HW_ / 4) / BPB;         // 2048 float4 groups
constexpr int GPT = GROUPS_PER_BLOCK / THREADS;           // 8 groups per thread
constexpr int UNROLL = 4;
constexpr int PASSES = GPT / UNROLL;                      // 2
constexpr unsigned TOTAL_BLOCKS = BPB * BATCH;            // 1024

__global__ __launch_bounds__(THREADS) void hist_fused(const float* __restrict__ x,
                                                      unsigned* __restrict__ hist,
                                                      unsigned* __restrict__ counter,
                                                      float* __restrict__ out) {
    // Per-wave privatized histograms: 4 waves * 256 bins * 4B = 4 KiB LDS
    __shared__ unsigned lh[4][BINS];
    __shared__ unsigned islast;
    __shared__ float red[256];
    const int t = threadIdx.x;
    const int wave = t >> 6;
#pragma unroll
    for (int w = 0; w < 4; ++w) lh[w][t] = 0u;
    __syncthreads();

    const int b = blockIdx.y;
    const float* base = x + (size_t)b * 3 * HW_;
    const float4* __restrict__ p0 = (const float4*)(base);
    const float4* __restrict__ p1 = (const float4*)(base + HW_);
    const float4* __restrict__ p2 = (const float4*)(base + 2 * HW_);
    const int g0 = blockIdx.x * GROUPS_PER_BLOCK + t;

#pragma unroll
    for (int pass = 0; pass < PASSES; ++pass) {
        float4 A[UNROLL], Bc[UNROLL], Cc[UNROLL];
#pragma unroll
        for (int u = 0; u < UNROLL; ++u) {
            int g = g0 + (pass * UNROLL + u) * THREADS;
            A[u]  = p0[g];
            Bc[u] = p1[g];
            Cc[u] = p2[g];
        }
#pragma unroll
        for (int u = 0; u < UNROLL; ++u) {
            // mean(x*255) = (a+b+c)*85 up to rounding; bin flips only at
            // integer boundaries (~1e-5 loss effect per flip, thr=0.103)
            float t0 = ((A[u].x + Bc[u].x) + Cc[u].x) * 85.0f;
            float t1 = ((A[u].y + Bc[u].y) + Cc[u].y) * 85.0f;
            float t2 = ((A[u].z + Bc[u].z) + Cc[u].z) * 85.0f;
            float t3 = ((A[u].w + Bc[u].w) + Cc[u].w) * 85.0f;
            int i0 = min(max((int)t0, 0), 255);   // trunc == astype(int32)
            int i1 = min(max((int)t1, 0), 255);
            int i2 = min(max((int)t2, 0), 255);
            int i3 = min(max((int)t3, 0), 255);
            atomicAdd(&lh[wave][i0], 1u);
            atomicAdd(&lh[wave][i1], 1u);
            atomicAdd(&lh[wave][i2], 1u);
            atomicAdd(&lh[wave][i3], 1u);
        }
    }
    __syncthreads();

    // Merge into per-batch global histogram (device-coherent-point atomics)
    unsigned total = lh[0][t] + lh[1][t] + lh[2][t] + lh[3][t];
    if (total) atomicAdd(&hist[b * BINS + t], total);

    // Each wave's hist atomics complete (vmcnt drain) at this barrier;
    // NO __threadfence — atomics are already globally visible.
    asm volatile("s_waitcnt vmcnt(0)" ::: "memory");
    __syncthreads();
    if (t == 0) {
        unsigned old = __hip_atomic_fetch_add(counter, 1u, __ATOMIC_RELAXED,
                                              __HIP_MEMORY_SCOPE_AGENT);
        islast = (old == TOTAL_BLOCKS - 1) ? 1u : 0u;
    }
    __syncthreads();
    if (!islast) return;

    // Last block: entropy. Thread t owns bin t; agent-scope atomic loads
    // bypass this XCD's (possibly stale) L1/L2.
    const float inv_np = 1.0f / (float)(HW_ + BINS);       // 1/262400
    float s = 0.0f;
#pragma unroll
    for (int bb = 0; bb < BATCH; ++bb) {
        unsigned cnt = __hip_atomic_load(&hist[bb * BINS + t], __ATOMIC_RELAXED,
                                         __HIP_MEMORY_SCOPE_AGENT);
        // bin-0 quirk: counts[:,0] = H*W, then +1 smoothing on every bin
        float h = (t == 0) ? ((float)HW_ + 1.0f) : ((float)cnt + 1.0f);
        float p = h * inv_np;
        s += p * logf(p);
    }
    red[t] = s;
    __syncthreads();
    for (int off = 128; off > 0; off >>= 1) {
        if (t < off) red[t] += red[t + off];
        __syncthreads();
    }
    if (t == 0) out[0] = red[0] * (1.0f / (float)BATCH);
}

extern "C" void kernel_launch(void* const* d_in, const int* in_sizes, int n_in,
                              void* d_out, int out_size, void* d_ws, size_t ws_size,
                              hipStream_t stream) {
    const float* x = (const float*)d_in[0];
    float* out = (float*)d_out;
    unsigned* hist = (unsigned*)d_ws;                  // 32*256 u32 = 32 KiB
    unsigned* counter = hist + BATCH * BINS;           // 1 u32

    // Zero hist + counter every call (ws is poisoned; determinism)
    hipMemsetAsync(d_ws, 0, (BATCH * BINS + 1) * sizeof(unsigned), stream);
    hist_fused<<<dim3(BPB, BATCH), dim3(THREADS), 0, stream>>>(x, hist, counter, out);
}

// Round 7
// 22.143 us; speedup vs baseline: 4.4289x; 1.8392x over previous
//
#include <hip/hip_runtime.h>

// color_entropy_loss: x [32,3,512,512] f32 -> scalar f32
//   temp = (x*255).mean(axis=1); idx = clip(int(temp),0,255)
//   per-batch 256-bin histogram; hist[0] forced to H*W; hist += 1
//   prob = hist/(H*W+256); loss = mean_b( sum(prob*log(prob)) )
//
// R7: R6 with compile fix — nontemporal loads via clang ext_vector_type
// (HIP_vector_type struct is rejected by __builtin_nontemporal_load).
// BPB=64 (8 blocks/CU), u16 partials, two-kernel skeleton.

typedef float vfloat4 __attribute__((ext_vector_type(4)));

constexpr int BATCH = 32;
constexpr int HW_ = 512 * 512;      // 262144
constexpr int BINS = 256;
constexpr int THREADS = 256;
constexpr int BPB = 64;                                   // blocks per batch -> 2048 blocks
constexpr int GROUPS_PER_BLOCK = (HW_ / 4) / BPB;         // 1024 float4 groups
constexpr int GPT = GROUPS_PER_BLOCK / THREADS;           // 4 groups per thread
constexpr int UNROLL = 4;
constexpr int PASSES = GPT / UNROLL;                      // 1

__global__ __launch_bounds__(THREADS) void hist_kernel(const float* __restrict__ x,
                                                       unsigned short* __restrict__ ws,
                                                       float* __restrict__ out) {
    // Per-wave privatized histograms: 4 waves * 256 bins * 4B = 4 KiB LDS
    __shared__ unsigned lh[4][BINS];
    const int t = threadIdx.x;
    const int wave = t >> 6;
#pragma unroll
    for (int w = 0; w < 4; ++w) lh[w][t] = 0u;
    if (blockIdx.x == 0 && blockIdx.y == 0 && t == 0) out[0] = 0.0f;  // K2 accumulates
    __syncthreads();

    const int b = blockIdx.y;
    const float* base = x + (size_t)b * 3 * HW_;
    const vfloat4* __restrict__ p0 = (const vfloat4*)(base);
    const vfloat4* __restrict__ p1 = (const vfloat4*)(base + HW_);
    const vfloat4* __restrict__ p2 = (const vfloat4*)(base + 2 * HW_);
    const int g0 = blockIdx.x * GROUPS_PER_BLOCK + t;

#pragma unroll
    for (int pass = 0; pass < PASSES; ++pass) {
        vfloat4 A[UNROLL], Bc[UNROLL], Cc[UNROLL];
#pragma unroll
        for (int u = 0; u < UNROLL; ++u) {
            int g = g0 + (pass * UNROLL + u) * THREADS;
            A[u]  = __builtin_nontemporal_load(p0 + g);   // streamed once, bypass L2
            Bc[u] = __builtin_nontemporal_load(p1 + g);
            Cc[u] = __builtin_nontemporal_load(p2 + g);
        }
#pragma unroll
        for (int u = 0; u < UNROLL; ++u) {
            // mean(x*255) = (a+b+c)*85 up to rounding; bin flips only at
            // integer boundaries (~1e-5 loss effect per flip, thr=0.103)
            float t0 = ((A[u].x + Bc[u].x) + Cc[u].x) * 85.0f;
            float t1 = ((A[u].y + Bc[u].y) + Cc[u].y) * 85.0f;
            float t2 = ((A[u].z + Bc[u].z) + Cc[u].z) * 85.0f;
            float t3 = ((A[u].w + Bc[u].w) + Cc[u].w) * 85.0f;
            int i0 = min(max((int)t0, 0), 255);   // trunc == astype(int32)
            int i1 = min(max((int)t1, 0), 255);
            int i2 = min(max((int)t2, 0), 255);
            int i3 = min(max((int)t3, 0), 255);
            atomicAdd(&lh[wave][i0], 1u);
            atomicAdd(&lh[wave][i1], 1u);
            atomicAdd(&lh[wave][i2], 1u);
            atomicAdd(&lh[wave][i3], 1u);
        }
    }
    __syncthreads();
    // Non-atomic per-block u16 partial store (max count 4096/block fits u16;
    // every slot written every call -> no zeroing needed)
    unsigned total = lh[0][t] + lh[1][t] + lh[2][t] + lh[3][t];
    ws[((size_t)(b * BPB + blockIdx.x)) * BINS + t] = (unsigned short)total;
}

__global__ __launch_bounds__(256) void entropy_kernel(const unsigned short* __restrict__ ws,
                                                      float* __restrict__ out) {
    const int t = threadIdx.x;
    const int b = blockIdx.x;
    unsigned cnt = 0;
#pragma unroll 8
    for (int blk = 0; blk < BPB; ++blk)
        cnt += ws[((size_t)(b * BPB + blk)) * BINS + t];   // coalesced 128B/wave

    const float inv_np = 1.0f / (float)(HW_ + BINS);       // 1/262400
    // bin-0 quirk: counts[:,0] = H*W, then +1 smoothing on every bin
    float hist = (t == 0) ? ((float)HW_ + 1.0f) : ((float)cnt + 1.0f);
    float p = hist * inv_np;
    float v = p * logf(p);

    __shared__ float red[256];
    red[t] = v;
    __syncthreads();
    for (int off = 128; off > 0; off >>= 1) {
        if (t < off) red[t] += red[t + off];
        __syncthreads();
    }
    if (t == 0) atomicAdd(out, red[0] * (1.0f / (float)BATCH));
}

extern "C" void kernel_launch(void* const* d_in, const int* in_sizes, int n_in,
                              void* d_out, int out_size, void* d_ws, size_t ws_size,
                              hipStream_t stream) {
    const float* x = (const float*)d_in[0];
    float* out = (float*)d_out;
    unsigned short* ws = (unsigned short*)d_ws;   // 2048*256*2 = 1 MiB used

    hist_kernel<<<dim3(BPB, BATCH), dim3(THREADS), 0, stream>>>(x, ws, out);
    entropy_kernel<<<dim3(BATCH), dim3(256), 0, stream>>>(ws, out);
}